// Round 1
// 264.027 us; speedup vs baseline: 1.0393x; 1.0393x over previous
//
#include <hip/hip_runtime.h>

typedef _Float16 v8h __attribute__((ext_vector_type(8)));
typedef _Float16 v4h __attribute__((ext_vector_type(4)));
typedef _Float16 v2h __attribute__((ext_vector_type(2)));
typedef float v4f __attribute__((ext_vector_type(4)));

// ---------------- async global->LDS, 16B per lane ----------------
__device__ __forceinline__ void gl16(const void* g, void* l) {
    __builtin_amdgcn_global_load_lds(
        (const __attribute__((address_space(1))) unsigned int*)g,
        (__attribute__((address_space(3))) unsigned int*)l, 16, 0, 0);
}

// wave-local LDS fence: all outstanding LDS ops complete (wave is lockstep)
__device__ __forceinline__ void wave_lds_fence() {
    asm volatile("s_waitcnt lgkmcnt(0)" ::: "memory");
}

// ---------------- fused converts: x (fp32->fp16) and W (fp32 -> Wt fp16) ----------------
__global__ __launch_bounds__(256) void k_cvt(const float* __restrict__ x,
                                             _Float16* __restrict__ x16,
                                             const float* __restrict__ W,
                                             _Float16* __restrict__ Wt) {
    if (blockIdx.x < 8192) {
        int i = (blockIdx.x * 256 + threadIdx.x) * 8;
        float4 a = *(const float4*)(x + i);
        float4 b = *(const float4*)(x + i + 4);
        v8h h;
        h[0] = (_Float16)a.x; h[1] = (_Float16)a.y; h[2] = (_Float16)a.z; h[3] = (_Float16)a.w;
        h[4] = (_Float16)b.x; h[5] = (_Float16)b.y; h[6] = (_Float16)b.z; h[7] = (_Float16)b.w;
        *(v8h*)(x16 + i) = h;
    } else {
        __shared__ float T[64][68];
        int bid = blockIdx.x - 8192;
        int k0 = (bid & 15) * 64;
        int n0 = (bid >> 4) * 64;
        int t = threadIdx.x;
        int tr = t >> 4;   // 0..15
        int tc = t & 15;   // 0..15
#pragma unroll
        for (int rr = 0; rr < 4; rr++) {
            int kk = rr * 16 + tr;
            float4 v = *(const float4*)(W + (size_t)(k0 + kk) * 3072 + n0 + tc * 4);
            T[kk][tc * 4 + 0] = v.x; T[kk][tc * 4 + 1] = v.y;
            T[kk][tc * 4 + 2] = v.z; T[kk][tc * 4 + 3] = v.w;
        }
        __syncthreads();
#pragma unroll
        for (int ww = 0; ww < 4; ww++) {
            int nn = ww * 16 + tr;
            v4h h;
#pragma unroll
            for (int i = 0; i < 4; i++) h[i] = (_Float16)T[tc * 4 + i][nn];
            *(v4h*)(Wt + (size_t)(n0 + nn) * 1024 + k0 + tc * 4) = h;
        }
    }
}

// ---------------- GEMM: qkv16[16384][3072] = (A(fp16) @ Bt(fp16)^T + bias) as fp16 ----------------
// 256x256 tile, BK=64, 512 threads = 8 waves (2 M x 4 N), each wave 128x64 output.
// 8-phase schedule (T3+T4): per phase {ds_read frag subtile, 1 half-tile global_load_lds
// prefetch, s_barrier, setprio(1), 16 MFMA, setprio(0), [counted vmcnt], s_barrier}.
// LDS XOR-swizzle (T2): slot ^= row&7 on 16B slots; applied on the GLOBAL source during
// staging (global_load_lds dest must stay linear) and on the ds_read slot index.
// vmcnt ledger (2 loads per half-tile, per wave):
//   iter i: ph1: A(t+1)h0  ph2: A(t+1)h1,B(t+2)h0  ph3: B(t+2)h1
//           ph5: A(t+2)h0  ph6: A(t+2)h1           ph7: B(t+3)h0  ph8: B(t+3)h1
//   gate at ph4: need A(t+1),B(t+1) landed -> newest 4 = B(t+2) -> vmcnt(4)
//   gate at ph8: need A(t+2),B(t+2) landed -> newest 4 = B(t+3) -> vmcnt(4)
//   last iter: ph4 drains to vmcnt(0) (A(15) is the newest issue), no staging after.

#define MFMA16(q, A0K0, A0K1, A1K0, A1K1)                                                   \
    _Pragma("unroll")                                                                       \
    for (int ni = 0; ni < 4; ni++) {                                                        \
        acc[2*(q)][ni]   = __builtin_amdgcn_mfma_f32_16x16x32_f16(A0K0, bf[ni][0], acc[2*(q)][ni], 0, 0, 0);   \
        acc[2*(q)][ni]   = __builtin_amdgcn_mfma_f32_16x16x32_f16(A0K1, bf[ni][1], acc[2*(q)][ni], 0, 0, 0);   \
        acc[2*(q)+1][ni] = __builtin_amdgcn_mfma_f32_16x16x32_f16(A1K0, bf[ni][0], acc[2*(q)+1][ni], 0, 0, 0); \
        acc[2*(q)+1][ni] = __builtin_amdgcn_mfma_f32_16x16x32_f16(A1K1, bf[ni][1], acc[2*(q)+1][ni], 0, 0, 0); \
    }

#define PHASE(XB, q, PRE, WAIT)                                                             \
    {                                                                                       \
        v8h a0k0 = *(const v8h*)&XB[aoff + (2*(q)) * 1024];                                 \
        v8h a0k1 = *(const v8h*)&XB[(aoff ^ 32) + (2*(q)) * 1024];                          \
        v8h a1k0 = *(const v8h*)&XB[aoff + (2*(q)+1) * 1024];                               \
        v8h a1k1 = *(const v8h*)&XB[(aoff ^ 32) + (2*(q)+1) * 1024];                        \
        PRE                                                                                 \
        __builtin_amdgcn_s_barrier();                                                       \
        __builtin_amdgcn_s_setprio(1);                                                      \
        MFMA16(q, a0k0, a0k1, a1k0, a1k1)                                                   \
        __builtin_amdgcn_s_setprio(0);                                                      \
        WAIT                                                                                \
        __builtin_amdgcn_s_barrier();                                                       \
    }

#define LOADB(XB)                                                                           \
    _Pragma("unroll")                                                                       \
    for (int ni = 0; ni < 4; ni++) {                                                        \
        bf[ni][0] = *(const v8h*)&XB[boff + ni * 1024];                                     \
        bf[ni][1] = *(const v8h*)&XB[(boff ^ 32) + ni * 1024];                              \
    }

#define STAGE_A(t, h, j) gl16(aS + (size_t)((h) * 128 + (j) * 8) * 1024 + (t) * 64,         \
                              &As[(t) & 1][((h) * 128 + ldsRow + (j) * 8) * 64])
#define STAGE_B(t, h, j) gl16(bS + (size_t)((h) * 128 + (j) * 8) * 1024 + (t) * 64,         \
                              &Bs[(t) & 1][((h) * 128 + ldsRow + (j) * 8) * 64])

__global__ __launch_bounds__(512, 2) void k_gemm(const _Float16* __restrict__ A,
                                                 const _Float16* __restrict__ Bt,
                                                 const float* __restrict__ bias,
                                                 _Float16* __restrict__ C) {
    __shared__ __align__(16) _Float16 As[2][256 * 64];   // 64 KiB
    __shared__ __align__(16) _Float16 Bs[2][256 * 64];   // 64 KiB

    // grid 64x12 = 768 wg; 768 % 8 == 0 -> simple bijective XCD swizzle (T1)
    int wg = blockIdx.x;
    wg = (wg & 7) * 96 + (wg >> 3);
    int bm = wg / 12, bn = wg % 12;
    int m0 = bm * 256, n0 = bn * 256;

    int tid = threadIdx.x;
    int w = tid >> 6;            // 0..7
    int lane = tid & 63;
    int l15 = lane & 15, quad = lane >> 4;
    int wm = (w >> 2) * 128;     // 0 or 128
    int wn = (w & 3) * 64;       // 0,64,128,192

    // staging: per-lane global source with inverse-swizzled k slot (rule #21)
    int rl = lane >> 3;                        // row within 8-row chunk, == row&7
    int ksw = ((lane & 7) ^ rl) * 8;           // swizzled 16B k-slot
    const _Float16* aS = A  + (size_t)(m0 + w * 16 + rl) * 1024 + ksw;
    const _Float16* bS = Bt + (size_t)(n0 + w * 16 + rl) * 1024 + ksw;
    int ldsRow = w * 16;

    // ds_read per-lane fragment offsets (swizzled slot; ^32 toggles k-half)
    int swz = (quad ^ (l15 & 7)) * 8;
    int aoff = (wm + l15) * 64 + swz;
    int boff = (wn + l15) * 64 + swz;

    v4f acc[8][4] = {};
    v8h bf[4][2];

    // prologue: stage K-tiles 0 (buf0) and 1 (buf1)
    STAGE_A(0, 0, 0); STAGE_A(0, 0, 1); STAGE_A(0, 1, 0); STAGE_A(0, 1, 1);
    STAGE_B(0, 0, 0); STAGE_B(0, 0, 1); STAGE_B(0, 1, 0); STAGE_B(0, 1, 1);
    STAGE_A(1, 0, 0); STAGE_A(1, 0, 1); STAGE_A(1, 1, 0); STAGE_A(1, 1, 1);
    STAGE_B(1, 0, 0); STAGE_B(1, 0, 1); STAGE_B(1, 1, 0); STAGE_B(1, 1, 1);
    asm volatile("s_waitcnt vmcnt(8)" ::: "memory");   // tile 0 landed; tile 1 in flight
    __builtin_amdgcn_s_barrier();

    for (int it = 0; it < 8; ++it) {
        int t = it * 2;
        // ---- K-tile t (buf0), phases 1-4 ----
        LOADB(Bs[0])
        PHASE(As[0], 0,
              if (it >= 1) { STAGE_A(t + 1, 0, 0); STAGE_A(t + 1, 0, 1); },
              )
        PHASE(As[0], 1,
              if (it >= 1) { STAGE_A(t + 1, 1, 0); STAGE_A(t + 1, 1, 1); }
              if (it <= 6) { STAGE_B(t + 2, 0, 0); STAGE_B(t + 2, 0, 1); },
              )
        PHASE(As[0], 2,
              if (it <= 6) { STAGE_B(t + 2, 1, 0); STAGE_B(t + 2, 1, 1); },
              )
        PHASE(As[0], 3,
              ,
              if (it == 7) { asm volatile("s_waitcnt vmcnt(0)" ::: "memory"); }
              else         { asm volatile("s_waitcnt vmcnt(4)" ::: "memory"); })
        // ---- K-tile t+1 (buf1), phases 5-8 ----
        LOADB(Bs[1])
        PHASE(As[1], 0,
              if (it <= 6) { STAGE_A(t + 2, 0, 0); STAGE_A(t + 2, 0, 1); },
              )
        PHASE(As[1], 1,
              if (it <= 6) { STAGE_A(t + 2, 1, 0); STAGE_A(t + 2, 1, 1); },
              )
        PHASE(As[1], 2,
              if (it <= 6) { STAGE_B(t + 3, 0, 0); STAGE_B(t + 3, 0, 1); },
              )
        PHASE(As[1], 3,
              if (it <= 6) { STAGE_B(t + 3, 1, 0); STAGE_B(t + 3, 1, 1); },
              if (it <= 6) { asm volatile("s_waitcnt vmcnt(4)" ::: "memory"); })
    }

    // epilogue: D row = quad*4 + r (m), col = l15 (n); add bias, cast fp16
#pragma unroll
    for (int ni = 0; ni < 4; ni++) {
        int n = n0 + wn + ni * 16 + l15;
        float bv = bias[n];
#pragma unroll
        for (int mi = 0; mi < 8; mi++) {
            int mbase = m0 + wm + mi * 16 + quad * 4;
#pragma unroll
            for (int r = 0; r < 4; r++)
                C[(size_t)(mbase + r) * 3072 + n] = (_Float16)(acc[mi][ni][r] + bv);
        }
    }
}

// ---------------- attention: one wave per position, global-direct fragments ----------------
// qkv row layout per pos: head h occupies halves [h*192, h*192+192): q(64)|k(64)|v(64).
// Q/K MFMA fragments and V segments load DIRECTLY from global (coalesced, every byte
// used once); only the 16x16 P matrix round-trips through LDS (h-row transpose).
__global__ __launch_bounds__(256) void k_attn(const _Float16* __restrict__ qkv,
                                              float* __restrict__ out) {
    __shared__ __align__(16) _Float16 Pb[4][16 * 24];   // P fp16, 48 B row stride
    int tid = threadIdx.x;
    int w = tid >> 6, lane = tid & 63;
    int pos = blockIdx.x * 4 + w;
    _Float16* P = Pb[w];
    const _Float16* src = qkv + (size_t)pos * 3072;
    int l15 = lane & 15, quad = lane >> 4;

    // ---- issue all global loads up-front (V overlaps QK+softmax) ----
    const _Float16* hrow = src + l15 * 192;            // head row l15
    v8h a0 = *(const v8h*)(hrow + quad * 8);           // Q d 0..31
    v8h a1 = *(const v8h*)(hrow + 32 + quad * 8);      // Q d 32..63
    v8h b0 = *(const v8h*)(hrow + 64 + quad * 8);      // K d 0..31
    v8h b1 = *(const v8h*)(hrow + 96 + quad * 8);      // K d 32..63
    int dl = lane & 15;                                // d segment dl*4..+4
    v4h vseg[16];
#pragma unroll
    for (int g = 0; g < 16; g++)
        vseg[g] = *(const v4h*)(src + g * 192 + 128 + dl * 4);

    {   // S = QK^T via 2x mfma_16x16x32; lane holds S[h=quad*4+r][g=l15]
        v4f s = {};
        s = __builtin_amdgcn_mfma_f32_16x16x32_f16(a0, b0, s, 0, 0, 0);
        s = __builtin_amdgcn_mfma_f32_16x16x32_f16(a1, b1, s, 0, 0, 0);
        float e4[4];
#pragma unroll
        for (int r = 0; r < 4; r++) {
            float sv = s[r] - 20.0f;
            e4[r] = (sv > 20.0f || sv < -20.0f) ? 0.0f : __expf(sv);
        }
        // denom: sum over g = sum across l15 (xor 1,2,4,8)
#pragma unroll
        for (int r = 0; r < 4; r++) {
            float t = e4[r];
            t += __shfl_xor(t, 1, 64);
            t += __shfl_xor(t, 2, 64);
            t += __shfl_xor(t, 4, 64);
            t += __shfl_xor(t, 8, 64);
            P[(quad * 4 + r) * 24 + l15] = (_Float16)(e4[r] / t);
        }
    }
    wave_lds_fence();

    {   // out[h][d] = sum_g P[h][g] * V[g][d]
        // lane owns h = 4t + quad for t=0..3, d-range = dl*4 .. +4
        v8h p0[4], p1[4];
#pragma unroll
        for (int t = 0; t < 4; t++) {
            const _Float16* Pr = P + (4 * t + quad) * 24;
            p0[t] = *(const v8h*)Pr;
            p1[t] = *(const v8h*)(Pr + 8);
        }
        v2h o[4][2] = {};
#pragma unroll
        for (int g = 0; g < 16; g++) {
            v2h va; va[0] = vseg[g][0]; va[1] = vseg[g][1];
            v2h vb; vb[0] = vseg[g][2]; vb[1] = vseg[g][3];
#pragma unroll
            for (int t = 0; t < 4; t++) {
                _Float16 ph = (g < 8) ? p0[t][g] : p1[t][g - 8];
                v2h p2; p2[0] = ph; p2[1] = ph;
                o[t][0] = p2 * va + o[t][0];
                o[t][1] = p2 * vb + o[t][1];
            }
        }
        float* dst = out + (size_t)pos * 1024;
#pragma unroll
        for (int t = 0; t < 4; t++) {
            float4 v;
            v.x = (float)o[t][0][0];
            v.y = (float)o[t][0][1];
            v.z = (float)o[t][1][0];
            v.w = (float)o[t][1][1];
            *(float4*)(dst + t * 256 + lane * 4) = v;  // fully contiguous per instr
        }
    }
}

extern "C" void kernel_launch(void* const* d_in, const int* in_sizes, int n_in,
                              void* d_out, int out_size, void* d_ws, size_t ws_size,
                              hipStream_t stream) {
    (void)in_sizes; (void)n_in; (void)out_size; (void)ws_size;
    const float* x  = (const float*)d_in[0];  // [4,4096,1024]
    const float* Wq = (const float*)d_in[1];  // [1024,3072]
    const float* bq = (const float*)d_in[2];  // [3072]
    float* out = (float*)d_out;               // [4,4096,16,64] fp32 (64 MiB)

    // x16 (32 MiB) + wt16 (6 MiB) live INSIDE d_out — dead before k_attn overwrites it.
    char* ob = (char*)d_out;
    _Float16* x16   = (_Float16*)ob;                   // 32 MiB @ d_out+0
    _Float16* wt16  = (_Float16*)(ob + (48u << 20));   // 6 MiB  @ d_out+48MiB
    _Float16* qkv16 = (_Float16*)d_ws;                 // 96 MiB

    k_cvt<<<8960, 256, 0, stream>>>(x, x16, Wq, wt16);
    k_gemm<<<768, 512, 0, stream>>>(x16, wt16, bq, qkv16);
    k_attn<<<4096, 256, 0, stream>>>(qkv16, out);
}

// Round 2
// 263.000 us; speedup vs baseline: 1.0433x; 1.0039x over previous
//
#include <hip/hip_runtime.h>

typedef _Float16 v8h __attribute__((ext_vector_type(8)));
typedef _Float16 v4h __attribute__((ext_vector_type(4)));
typedef _Float16 v2h __attribute__((ext_vector_type(2)));
typedef float v4f __attribute__((ext_vector_type(4)));

// ---------------- async global->LDS, 16B per lane ----------------
__device__ __forceinline__ void gl16(const void* g, void* l) {
    __builtin_amdgcn_global_load_lds(
        (const __attribute__((address_space(1))) unsigned int*)g,
        (__attribute__((address_space(3))) unsigned int*)l, 16, 0, 0);
}

// wave-local LDS fence: all outstanding LDS ops complete (wave is lockstep)
__device__ __forceinline__ void wave_lds_fence() {
    asm volatile("s_waitcnt lgkmcnt(0)" ::: "memory");
}

// LDS byte address (32-bit) of a shared-memory pointer, for inline-asm ds ops
__device__ __forceinline__ unsigned lds_addr(const void* p) {
    return (unsigned)(size_t)(const __attribute__((address_space(3))) char*)p;
}

// ---------------- fused converts: x (fp32->fp16) and W (fp32 -> Wt fp16) ----------------
__global__ __launch_bounds__(256) void k_cvt(const float* __restrict__ x,
                                             _Float16* __restrict__ x16,
                                             const float* __restrict__ W,
                                             _Float16* __restrict__ Wt) {
    if (blockIdx.x < 8192) {
        int i = (blockIdx.x * 256 + threadIdx.x) * 8;
        float4 a = *(const float4*)(x + i);
        float4 b = *(const float4*)(x + i + 4);
        v8h h;
        h[0] = (_Float16)a.x; h[1] = (_Float16)a.y; h[2] = (_Float16)a.z; h[3] = (_Float16)a.w;
        h[4] = (_Float16)b.x; h[5] = (_Float16)b.y; h[6] = (_Float16)b.z; h[7] = (_Float16)b.w;
        *(v8h*)(x16 + i) = h;
    } else {
        __shared__ float T[64][68];
        int bid = blockIdx.x - 8192;
        int k0 = (bid & 15) * 64;
        int n0 = (bid >> 4) * 64;
        int t = threadIdx.x;
        int tr = t >> 4;   // 0..15
        int tc = t & 15;   // 0..15
#pragma unroll
        for (int rr = 0; rr < 4; rr++) {
            int kk = rr * 16 + tr;
            float4 v = *(const float4*)(W + (size_t)(k0 + kk) * 3072 + n0 + tc * 4);
            T[kk][tc * 4 + 0] = v.x; T[kk][tc * 4 + 1] = v.y;
            T[kk][tc * 4 + 2] = v.z; T[kk][tc * 4 + 3] = v.w;
        }
        __syncthreads();
#pragma unroll
        for (int ww = 0; ww < 4; ww++) {
            int nn = ww * 16 + tr;
            v4h h;
#pragma unroll
            for (int i = 0; i < 4; i++) h[i] = (_Float16)T[tc * 4 + i][nn];
            *(v4h*)(Wt + (size_t)(n0 + nn) * 1024 + k0 + tc * 4) = h;
        }
    }
}

// ---------------- GEMM: qkv16[16384][3072] = (A(fp16) @ Bt(fp16)^T + bias) as fp16 ----------------
// 256x256 tile, BK=64, 512 threads = 8 waves (2 M x 4 N), each wave 128x64 output.
// 8-phase schedule with FULLY MANUAL waitcnts: fragment reads are inline-asm ds_read_b128
// (compiler inserts no waits for them); counted lgkmcnt splits each phase's 16 MFMAs into
// a k0-group and k1-group so ds_read latency hides under MFMA (rule #18: sched_barrier(0)
// after each wait pins MFMA placement). Staging/vmcnt ledger identical to previous round:
//   gates at ph4/ph8 only, vmcnt(4) steady state (leaves newest half-tile pair in flight),
//   vmcnt(0) at it==7 ph4. LDS XOR-swizzle on 16B slots (verified: 0 bank conflicts).

#define MFMA(a, b, c) __builtin_amdgcn_mfma_f32_16x16x32_f16(a, b, c, 0, 0, 0)
#define DSR(d, a, IMM) asm volatile("ds_read_b128 %0, %1 offset:%2" : "=v"(d) : "v"(a), "n"(IMM))
#define LGKM(N) asm volatile("s_waitcnt lgkmcnt(" #N ")" ::: "memory")
#define SB0() __builtin_amdgcn_sched_barrier(0)
#define BAR() __builtin_amdgcn_s_barrier()

// issue order matters for counted lgkm: [B.k0 x4, a.k0 x2] = first 6, then [B.k1 x4, a.k1 x2]
#define ISSUE_B(BO)                                                                         \
    DSR(bf[0][0], vB0, (BO));        DSR(bf[1][0], vB0, (BO) + 2048);                       \
    DSR(bf[2][0], vB0, (BO) + 4096); DSR(bf[3][0], vB0, (BO) + 6144);                       \
    DSR(a0k0, vA0, (BO));            DSR(a1k0, vA0, (BO) + 2048);                           \
    DSR(bf[0][1], vB1, (BO));        DSR(bf[1][1], vB1, (BO) + 2048);                       \
    DSR(bf[2][1], vB1, (BO) + 4096); DSR(bf[3][1], vB1, (BO) + 6144);                       \
    DSR(a0k1, vA1, (BO));            DSR(a1k1, vA1, (BO) + 2048);

#define ISSUE_A(q, BO)                                                                      \
    DSR(a0k0, vA0, (BO) + (2*(q)) * 2048);   DSR(a1k0, vA0, (BO) + (2*(q)+1) * 2048);       \
    DSR(a0k1, vA1, (BO) + (2*(q)) * 2048);   DSR(a1k1, vA1, (BO) + (2*(q)+1) * 2048);

#define MF_K0(q)                                                                            \
    _Pragma("unroll")                                                                       \
    for (int ni = 0; ni < 4; ni++) {                                                        \
        acc[2*(q)][ni]   = MFMA(a0k0, bf[ni][0], acc[2*(q)][ni]);                           \
        acc[2*(q)+1][ni] = MFMA(a1k0, bf[ni][0], acc[2*(q)+1][ni]);                         \
    }
#define MF_K1(q)                                                                            \
    _Pragma("unroll")                                                                       \
    for (int ni = 0; ni < 4; ni++) {                                                        \
        acc[2*(q)][ni]   = MFMA(a0k1, bf[ni][1], acc[2*(q)][ni]);                           \
        acc[2*(q)+1][ni] = MFMA(a1k1, bf[ni][1], acc[2*(q)+1][ni]);                         \
    }

// phase with B-tile fragment loads (q=0): 12 reads, counted split 6/0
#define PH_FIRST(BO, PRE, GATE)                                                             \
    ISSUE_B(BO)                                                                             \
    PRE                                                                                     \
    BAR();                                                                                  \
    LGKM(6); SB0(); __builtin_amdgcn_s_setprio(1);                                          \
    MF_K0(0)                                                                                \
    LGKM(0); SB0();                                                                         \
    MF_K1(0)                                                                                \
    __builtin_amdgcn_s_setprio(0);                                                          \
    GATE                                                                                    \
    BAR();

// phases q=1..3: 4 reads, counted split 2/0
#define PH(q, BO, PRE, GATE)                                                                \
    ISSUE_A(q, BO)                                                                          \
    PRE                                                                                     \
    BAR();                                                                                  \
    LGKM(2); SB0(); __builtin_amdgcn_s_setprio(1);                                          \
    MF_K0(q)                                                                                \
    LGKM(0); SB0();                                                                         \
    MF_K1(q)                                                                                \
    __builtin_amdgcn_s_setprio(0);                                                          \
    GATE                                                                                    \
    BAR();

#define STAGE_A(t, h, j) gl16(aS + (size_t)((h) * 128 + (j) * 8) * 1024 + (t) * 64,         \
                              &As[(t) & 1][((h) * 128 + ldsRow + (j) * 8) * 64])
#define STAGE_B(t, h, j) gl16(bS + (size_t)((h) * 128 + (j) * 8) * 1024 + (t) * 64,         \
                              &Bs[(t) & 1][((h) * 128 + ldsRow + (j) * 8) * 64])

__global__ __launch_bounds__(512, 2) void k_gemm(const _Float16* __restrict__ A,
                                                 const _Float16* __restrict__ Bt,
                                                 const float* __restrict__ bias,
                                                 _Float16* __restrict__ C) {
    __shared__ __align__(16) _Float16 As[2][256 * 64];   // 64 KiB
    __shared__ __align__(16) _Float16 Bs[2][256 * 64];   // 64 KiB

    // grid 64x12 = 768 wg; 768 % 8 == 0 -> simple bijective XCD swizzle (T1)
    int wg = blockIdx.x;
    wg = (wg & 7) * 96 + (wg >> 3);
    int bm = wg / 12, bn = wg % 12;
    int m0 = bm * 256, n0 = bn * 256;

    int tid = threadIdx.x;
    int w = tid >> 6;            // 0..7
    int lane = tid & 63;
    int l15 = lane & 15, quad = lane >> 4;
    int wm = (w >> 2) * 128;     // 0 or 128
    int wn = (w & 3) * 64;       // 0,64,128,192

    // staging: per-lane global source with inverse-swizzled k slot (rule #21)
    int rl = lane >> 3;                        // row within 8-row chunk, == row&7
    int ksw = ((lane & 7) ^ rl) * 8;           // swizzled 16B k-slot
    const _Float16* aS = A  + (size_t)(m0 + w * 16 + rl) * 1024 + ksw;
    const _Float16* bS = Bt + (size_t)(n0 + w * 16 + rl) * 1024 + ksw;
    int ldsRow = w * 16;

    // ds_read per-lane fragment base addresses (loop-invariant VGPRs, byte units)
    int swz = (quad ^ (l15 & 7)) * 8;
    int aoff = (wm + l15) * 64 + swz;
    int boff = (wn + l15) * 64 + swz;
    unsigned vA0 = lds_addr(&As[0][aoff]);
    unsigned vA1 = lds_addr(&As[0][aoff ^ 32]);
    unsigned vB0 = lds_addr(&Bs[0][boff]);
    unsigned vB1 = lds_addr(&Bs[0][boff ^ 32]);

    v4f acc[8][4] = {};
    v8h bf[4][2];
    v8h a0k0, a1k0, a0k1, a1k1;

    // prologue: stage K-tiles 0 (buf0) and 1 (buf1)
    STAGE_A(0, 0, 0); STAGE_A(0, 0, 1); STAGE_A(0, 1, 0); STAGE_A(0, 1, 1);
    STAGE_B(0, 0, 0); STAGE_B(0, 0, 1); STAGE_B(0, 1, 0); STAGE_B(0, 1, 1);
    STAGE_A(1, 0, 0); STAGE_A(1, 0, 1); STAGE_A(1, 1, 0); STAGE_A(1, 1, 1);
    STAGE_B(1, 0, 0); STAGE_B(1, 0, 1); STAGE_B(1, 1, 0); STAGE_B(1, 1, 1);
    asm volatile("s_waitcnt vmcnt(8)" ::: "memory");   // tile 0 landed; tile 1 in flight
    BAR();

    for (int it = 0; it < 8; ++it) {
        int t = it * 2;
        // ---- K-tile t (buf0), phases 1-4 ----
        PH_FIRST(0,
                 if (it >= 1) { STAGE_A(t + 1, 0, 0); STAGE_A(t + 1, 0, 1); },
                 )
        PH(1, 0,
           if (it >= 1) { STAGE_A(t + 1, 1, 0); STAGE_A(t + 1, 1, 1); }
           if (it <= 6) { STAGE_B(t + 2, 0, 0); STAGE_B(t + 2, 0, 1); },
           )
        PH(2, 0,
           if (it <= 6) { STAGE_B(t + 2, 1, 0); STAGE_B(t + 2, 1, 1); },
           )
        PH(3, 0,
           ,
           if (it == 7) { asm volatile("s_waitcnt vmcnt(0)" ::: "memory"); }
           else         { asm volatile("s_waitcnt vmcnt(4)" ::: "memory"); })
        // ---- K-tile t+1 (buf1), phases 5-8 ----
        PH_FIRST(32768,
                 if (it <= 6) { STAGE_A(t + 2, 0, 0); STAGE_A(t + 2, 0, 1); },
                 )
        PH(1, 32768,
           if (it <= 6) { STAGE_A(t + 2, 1, 0); STAGE_A(t + 2, 1, 1); },
           )
        PH(2, 32768,
           if (it <= 6) { STAGE_B(t + 3, 0, 0); STAGE_B(t + 3, 0, 1); },
           )
        PH(3, 32768,
           if (it <= 6) { STAGE_B(t + 3, 1, 0); STAGE_B(t + 3, 1, 1); },
           if (it <= 6) { asm volatile("s_waitcnt vmcnt(4)" ::: "memory"); })
    }

    // epilogue: D row = quad*4 + r (m), col = l15 (n); add bias, cast fp16
#pragma unroll
    for (int ni = 0; ni < 4; ni++) {
        int n = n0 + wn + ni * 16 + l15;
        float bv = bias[n];
#pragma unroll
        for (int mi = 0; mi < 8; mi++) {
            int mbase = m0 + wm + mi * 16 + quad * 4;
#pragma unroll
            for (int r = 0; r < 4; r++)
                C[(size_t)(mbase + r) * 3072 + n] = (_Float16)(acc[mi][ni][r] + bv);
        }
    }
}

// ---------------- attention: one wave per position, global-direct fragments ----------------
// qkv row layout per pos: head h occupies halves [h*192, h*192+192): q(64)|k(64)|v(64).
// Q/K MFMA fragments and V segments load DIRECTLY from global (coalesced, every byte
// used once); only the 16x16 P matrix round-trips through LDS (h-row transpose).
__global__ __launch_bounds__(256) void k_attn(const _Float16* __restrict__ qkv,
                                              float* __restrict__ out) {
    __shared__ __align__(16) _Float16 Pb[4][16 * 24];   // P fp16, 48 B row stride
    int tid = threadIdx.x;
    int w = tid >> 6, lane = tid & 63;
    int pos = blockIdx.x * 4 + w;
    _Float16* P = Pb[w];
    const _Float16* src = qkv + (size_t)pos * 3072;
    int l15 = lane & 15, quad = lane >> 4;

    // ---- issue all global loads up-front (V overlaps QK+softmax) ----
    const _Float16* hrow = src + l15 * 192;            // head row l15
    v8h a0 = *(const v8h*)(hrow + quad * 8);           // Q d 0..31
    v8h a1 = *(const v8h*)(hrow + 32 + quad * 8);      // Q d 32..63
    v8h b0 = *(const v8h*)(hrow + 64 + quad * 8);      // K d 0..31
    v8h b1 = *(const v8h*)(hrow + 96 + quad * 8);      // K d 32..63
    int dl = lane & 15;                                // d segment dl*4..+4
    v4h vseg[16];
#pragma unroll
    for (int g = 0; g < 16; g++)
        vseg[g] = *(const v4h*)(src + g * 192 + 128 + dl * 4);

    {   // S = QK^T via 2x mfma_16x16x32; lane holds S[h=quad*4+r][g=l15]
        v4f s = {};
        s = __builtin_amdgcn_mfma_f32_16x16x32_f16(a0, b0, s, 0, 0, 0);
        s = __builtin_amdgcn_mfma_f32_16x16x32_f16(a1, b1, s, 0, 0, 0);
        float e4[4];
#pragma unroll
        for (int r = 0; r < 4; r++) {
            float sv = s[r] - 20.0f;
            e4[r] = (sv > 20.0f || sv < -20.0f) ? 0.0f : __expf(sv);
        }
        // denom: sum over g = sum across l15 (xor 1,2,4,8)
#pragma unroll
        for (int r = 0; r < 4; r++) {
            float t = e4[r];
            t += __shfl_xor(t, 1, 64);
            t += __shfl_xor(t, 2, 64);
            t += __shfl_xor(t, 4, 64);
            t += __shfl_xor(t, 8, 64);
            P[(quad * 4 + r) * 24 + l15] = (_Float16)(e4[r] / t);
        }
    }
    wave_lds_fence();

    {   // out[h][d] = sum_g P[h][g] * V[g][d]
        // lane owns h = 4t + quad for t=0..3, d-range = dl*4 .. +4
        v8h p0[4], p1[4];
#pragma unroll
        for (int t = 0; t < 4; t++) {
            const _Float16* Pr = P + (4 * t + quad) * 24;
            p0[t] = *(const v8h*)Pr;
            p1[t] = *(const v8h*)(Pr + 8);
        }
        v2h o[4][2] = {};
#pragma unroll
        for (int g = 0; g < 16; g++) {
            v2h va; va[0] = vseg[g][0]; va[1] = vseg[g][1];
            v2h vb; vb[0] = vseg[g][2]; vb[1] = vseg[g][3];
#pragma unroll
            for (int t = 0; t < 4; t++) {
                _Float16 ph = (g < 8) ? p0[t][g] : p1[t][g - 8];
                v2h p2; p2[0] = ph; p2[1] = ph;
                o[t][0] = p2 * va + o[t][0];
                o[t][1] = p2 * vb + o[t][1];
            }
        }
        float* dst = out + (size_t)pos * 1024;
#pragma unroll
        for (int t = 0; t < 4; t++) {
            float4 v;
            v.x = (float)o[t][0][0];
            v.y = (float)o[t][0][1];
            v.z = (float)o[t][1][0];
            v.w = (float)o[t][1][1];
            *(float4*)(dst + t * 256 + lane * 4) = v;  // fully contiguous per instr
        }
    }
}

extern "C" void kernel_launch(void* const* d_in, const int* in_sizes, int n_in,
                              void* d_out, int out_size, void* d_ws, size_t ws_size,
                              hipStream_t stream) {
    (void)in_sizes; (void)n_in; (void)out_size; (void)ws_size;
    const float* x  = (const float*)d_in[0];  // [4,4096,1024]
    const float* Wq = (const float*)d_in[1];  // [1024,3072]
    const float* bq = (const float*)d_in[2];  // [3072]
    float* out = (float*)d_out;               // [4,4096,16,64] fp32 (64 MiB)

    // x16 (32 MiB) + wt16 (6 MiB) live INSIDE d_out — dead before k_attn overwrites it.
    char* ob = (char*)d_out;
    _Float16* x16   = (_Float16*)ob;                   // 32 MiB @ d_out+0
    _Float16* wt16  = (_Float16*)(ob + (48u << 20));   // 6 MiB  @ d_out+48MiB
    _Float16* qkv16 = (_Float16*)d_ws;                 // 96 MiB

    k_cvt<<<8960, 256, 0, stream>>>(x, x16, Wq, wt16);
    k_gemm<<<768, 512, 0, stream>>>(x16, wt16, bq, qkv16);
    k_attn<<<4096, 256, 0, stream>>>(qkv16, out);
}

// Round 3
// 258.209 us; speedup vs baseline: 1.0627x; 1.0186x over previous
//
#include <hip/hip_runtime.h>

typedef _Float16 v8h __attribute__((ext_vector_type(8)));
typedef _Float16 v4h __attribute__((ext_vector_type(4)));
typedef _Float16 v2h __attribute__((ext_vector_type(2)));
typedef float v4f __attribute__((ext_vector_type(4)));
typedef float f32x16 __attribute__((ext_vector_type(16)));

// ---------------- async global->LDS, 16B per lane ----------------
__device__ __forceinline__ void gl16(const void* g, void* l) {
    __builtin_amdgcn_global_load_lds(
        (const __attribute__((address_space(1))) unsigned int*)g,
        (__attribute__((address_space(3))) unsigned int*)l, 16, 0, 0);
}

// wave-local LDS fence: all outstanding LDS ops complete (wave is lockstep)
__device__ __forceinline__ void wave_lds_fence() {
    asm volatile("s_waitcnt lgkmcnt(0)" ::: "memory");
}

// LDS byte address (32-bit) of a shared-memory pointer, for inline-asm ds ops
__device__ __forceinline__ unsigned lds_addr(const void* p) {
    return (unsigned)(size_t)(const __attribute__((address_space(3))) char*)p;
}

// ---------------- fused converts: x (fp32->fp16) and W (fp32 -> Wt fp16) ----------------
__global__ __launch_bounds__(256) void k_cvt(const float* __restrict__ x,
                                             _Float16* __restrict__ x16,
                                             const float* __restrict__ W,
                                             _Float16* __restrict__ Wt) {
    if (blockIdx.x < 8192) {
        int i = (blockIdx.x * 256 + threadIdx.x) * 8;
        float4 a = *(const float4*)(x + i);
        float4 b = *(const float4*)(x + i + 4);
        v8h h;
        h[0] = (_Float16)a.x; h[1] = (_Float16)a.y; h[2] = (_Float16)a.z; h[3] = (_Float16)a.w;
        h[4] = (_Float16)b.x; h[5] = (_Float16)b.y; h[6] = (_Float16)b.z; h[7] = (_Float16)b.w;
        *(v8h*)(x16 + i) = h;
    } else {
        __shared__ float T[64][68];
        int bid = blockIdx.x - 8192;
        int k0 = (bid & 15) * 64;
        int n0 = (bid >> 4) * 64;
        int t = threadIdx.x;
        int tr = t >> 4;   // 0..15
        int tc = t & 15;   // 0..15
#pragma unroll
        for (int rr = 0; rr < 4; rr++) {
            int kk = rr * 16 + tr;
            float4 v = *(const float4*)(W + (size_t)(k0 + kk) * 3072 + n0 + tc * 4);
            T[kk][tc * 4 + 0] = v.x; T[kk][tc * 4 + 1] = v.y;
            T[kk][tc * 4 + 2] = v.z; T[kk][tc * 4 + 3] = v.w;
        }
        __syncthreads();
#pragma unroll
        for (int ww = 0; ww < 4; ww++) {
            int nn = ww * 16 + tr;
            v4h h;
#pragma unroll
            for (int i = 0; i < 4; i++) h[i] = (_Float16)T[tc * 4 + i][nn];
            *(v4h*)(Wt + (size_t)(n0 + nn) * 1024 + k0 + tc * 4) = h;
        }
    }
}

// ---------------- GEMM: qkv16[16384][3072] = (A(fp16) @ Bt(fp16)^T + bias) as fp16 ----------------
// 256x256 tile, BK=64, 512 threads = 8 waves (2M x 4N), per-wave 128x64 via 4x2 of 32x32.
// mfma_f32_32x32x16_f16; phase = one K=16 step = 8 MFMA/wave; 8 phases per K-tile pair.
// REGISTER PREFETCH: phase p's head issues phase p+1's 6 ds_read_b128 into the alternate
// fragment set, so LDS service overlaps the MFMA drain (R2's serial-read stall removed).
// lgkmcnt(6) waits only the PREVIOUS head's reads; sched_barrier(0) pins MFMA placement.
// Staging (global_load_lds, vmcnt): ph1: A(t+1)+B(t+1); ph5: A(t+2); ph6: B(t+2).
// Gates vmcnt(0) at ph3/ph7 ends are exact drains (2-phase slack) before the cross-buffer
// fragment reads at ph4/ph8 heads. One s_barrier per phase.
// LDS XOR-swizzle on 16B slots unchanged (measured: 0 bank conflicts, results verified).

#define MFMA32(a, b, c) __builtin_amdgcn_mfma_f32_32x32x16_f16(a, b, c, 0, 0, 0)
#define DSR(d, a, IMM) asm volatile("ds_read_b128 %0, %1 offset:%2" : "=v"(d) : "v"(a), "n"(IMM))
#define LGKM(N) asm volatile("s_waitcnt lgkmcnt(" #N ")" ::: "memory")
#define VMCNT(N) asm volatile("s_waitcnt vmcnt(" #N ")" ::: "memory")
#define SB0() __builtin_amdgcn_sched_barrier(0)
#define BAR() __builtin_amdgcn_s_barrier()
#define PRIO1() __builtin_amdgcn_s_setprio(1)
#define PRIO0() __builtin_amdgcn_s_setprio(0)

// 6 fragment reads for one K=16 step: 4 A m-subtiles (+4096 each) + 2 B n-subtiles
#define RD6(AF, BF, VAK, VBK, IMM)                                      \
    DSR(AF[0], VAK, (IMM));        DSR(AF[1], VAK, (IMM) + 4096);       \
    DSR(AF[2], VAK, (IMM) + 8192); DSR(AF[3], VAK, (IMM) + 12288);      \
    DSR(BF[0], VBK, (IMM));        DSR(BF[1], VBK, (IMM) + 4096);

// 8 MFMAs of one K=16 step (all 8 accumulators, independent)
#define MF8(AF, BF)                                                     \
    _Pragma("unroll")                                                   \
    for (int mi = 0; mi < 4; mi++) {                                    \
        acc[mi][0] = MFMA32(AF[mi], BF[0], acc[mi][0]);                 \
        acc[mi][1] = MFMA32(AF[mi], BF[1], acc[mi][1]);                 \
    }

#define STAGE_A(t, h, j) gl16(aS + (size_t)((h) * 128 + (j) * 8) * 1024 + (t) * 64,         \
                              &As[(t) & 1][((h) * 128 + ldsRow + (j) * 8) * 64])
#define STAGE_B(t, h, j) gl16(bS + (size_t)((h) * 128 + (j) * 8) * 1024 + (t) * 64,         \
                              &Bs[(t) & 1][((h) * 128 + ldsRow + (j) * 8) * 64])
#define STAGE_A4(t) STAGE_A(t, 0, 0); STAGE_A(t, 0, 1); STAGE_A(t, 1, 0); STAGE_A(t, 1, 1)
#define STAGE_B4(t) STAGE_B(t, 0, 0); STAGE_B(t, 0, 1); STAGE_B(t, 1, 0); STAGE_B(t, 1, 1)

__global__ __launch_bounds__(512, 2) void k_gemm(const _Float16* __restrict__ A,
                                                 const _Float16* __restrict__ Bt,
                                                 const float* __restrict__ bias,
                                                 _Float16* __restrict__ C) {
    __shared__ __align__(16) _Float16 As[2][256 * 64];   // 64 KiB
    __shared__ __align__(16) _Float16 Bs[2][256 * 64];   // 64 KiB

    // grid 64x12 = 768 wg; 768 % 8 == 0 -> simple bijective XCD swizzle (T1)
    int wg = blockIdx.x;
    wg = (wg & 7) * 96 + (wg >> 3);
    int bm = wg / 12, bn = wg % 12;
    int m0 = bm * 256, n0 = bn * 256;

    int tid = threadIdx.x;
    int w = tid >> 6;            // 0..7
    int lane = tid & 63;
    int wm = (w >> 2) * 128;     // 0 or 128
    int wn = (w & 3) * 64;       // 0,64,128,192

    // staging: per-lane global source with inverse-swizzled k slot (rule #21)
    int rl = lane >> 3;                        // row within 8-row chunk, == row&7
    int ksw = ((lane & 7) ^ rl) * 8;           // swizzled 16B k-slot
    const _Float16* aS = A  + (size_t)(m0 + w * 16 + rl) * 1024 + ksw;
    const _Float16* bS = Bt + (size_t)(n0 + w * 16 + rl) * 1024 + ksw;
    int ldsRow = w * 16;

    // fragment read bases. 32x32x16 operand layout: row = lane&31, k = (lane>>5)*8 + i.
    // logical 16B slot for k-step kk = kk*2 + (lane>>5); physical slot = logical ^ (row&7).
    int row = lane & 31;
    int h = lane >> 5;
    int x = row & 7;
    unsigned aB = lds_addr(&As[0][0]) + (unsigned)((wm + row) * 128);
    unsigned bB = lds_addr(&Bs[0][0]) + (unsigned)((wn + row) * 128);
    unsigned vAk0 = aB + (unsigned)(((0 + h) ^ x) * 16);
    unsigned vAk1 = aB + (unsigned)(((2 + h) ^ x) * 16);
    unsigned vAk2 = aB + (unsigned)(((4 + h) ^ x) * 16);
    unsigned vAk3 = aB + (unsigned)(((6 + h) ^ x) * 16);
    unsigned vBk0 = bB + (unsigned)(((0 + h) ^ x) * 16);
    unsigned vBk1 = bB + (unsigned)(((2 + h) ^ x) * 16);
    unsigned vBk2 = bB + (unsigned)(((4 + h) ^ x) * 16);
    unsigned vBk3 = bB + (unsigned)(((6 + h) ^ x) * 16);

    f32x16 acc[4][2] = {};
    v8h a0f[4], b0f[2];   // fragment set F0
    v8h a1f[4], b1f[2];   // fragment set F1

    // prologue: stage K-tiles 0 (buf0) and 1 (buf1); 16 gl16
    STAGE_A4(0); STAGE_B4(0);
    STAGE_A4(1); STAGE_B4(1);
    VMCNT(8);                 // tile 0 landed; tile 1 (newest 8) in flight
    BAR();
    RD6(a0f, b0f, vAk0, vBk0, 0)   // F0 <- kk0 buf0

    for (int it = 0; it < 8; ++it) {
        int t = it * 2;
        // ph1: use F0 (kk0 b0); fill F1 <- kk1 b0; stage next tile-pair's odd tile
        RD6(a1f, b1f, vAk1, vBk1, 0)
        if (it >= 1) { STAGE_A4(t + 1); STAGE_B4(t + 1); }
        LGKM(6); SB0(); PRIO1();
        MF8(a0f, b0f)
        PRIO0(); BAR();
        // ph2: use F1 (kk1 b0); fill F0 <- kk2 b0
        RD6(a0f, b0f, vAk2, vBk2, 0)
        LGKM(6); SB0(); PRIO1();
        MF8(a1f, b1f)
        PRIO0(); BAR();
        // ph3: use F0 (kk2 b0); fill F1 <- kk3 b0; GATE: A(t+1),B(t+1) landed
        RD6(a1f, b1f, vAk3, vBk3, 0)
        LGKM(6); SB0(); PRIO1();
        MF8(a0f, b0f)
        PRIO0();
        VMCNT(0);
        BAR();
        // ph4: use F1 (kk3 b0); fill F0 <- kk0 buf1 (gated above)
        RD6(a0f, b0f, vAk0, vBk0, 32768)
        LGKM(6); SB0(); PRIO1();
        MF8(a1f, b1f)
        PRIO0(); BAR();
        // ph5: use F0 (kk0 b1); fill F1 <- kk1 b1; stage A(t+2) -> As[0]
        RD6(a1f, b1f, vAk1, vBk1, 32768)
        if (it <= 6) { STAGE_A4(t + 2); }
        LGKM(6); SB0(); PRIO1();
        MF8(a0f, b0f)
        PRIO0(); BAR();
        // ph6: use F1 (kk1 b1); fill F0 <- kk2 b1; stage B(t+2) -> Bs[0]
        RD6(a0f, b0f, vAk2, vBk2, 32768)
        if (it <= 6) { STAGE_B4(t + 2); }
        LGKM(6); SB0(); PRIO1();
        MF8(a1f, b1f)
        PRIO0(); BAR();
        // ph7: use F0 (kk2 b1); fill F1 <- kk3 b1; GATE: A(t+2),B(t+2) landed
        RD6(a1f, b1f, vAk3, vBk3, 32768)
        LGKM(6); SB0(); PRIO1();
        MF8(a0f, b0f)
        PRIO0();
        VMCNT(0);
        BAR();
        // ph8: use F1 (kk3 b1); fill F0 <- kk0 buf0 of next iteration (gated above)
        if (it <= 6) {
            RD6(a0f, b0f, vAk0, vBk0, 0)
            LGKM(6);
        } else {
            LGKM(0);
        }
        SB0(); PRIO1();
        MF8(a1f, b1f)
        PRIO0(); BAR();
    }

    // epilogue: 32x32 C/D layout: col = lane&31, row = (r&3) + 8*(r>>2) + 4*(lane>>5)
    int cl = lane & 31;
    int rq = (lane >> 5) * 4;
#pragma unroll
    for (int nj = 0; nj < 2; nj++) {
        int n = n0 + wn + nj * 32 + cl;
        float bv = bias[n];
#pragma unroll
        for (int mi = 0; mi < 4; mi++) {
            int mb = m0 + wm + mi * 32 + rq;
#pragma unroll
            for (int r = 0; r < 16; r++) {
                int m = mb + (r & 3) + 8 * (r >> 2);
                C[(size_t)m * 3072 + n] = (_Float16)(acc[mi][nj][r] + bv);
            }
        }
    }
}

// ---------------- attention: one wave per position, global-direct fragments ----------------
// qkv row layout per pos: head h occupies halves [h*192, h*192+192): q(64)|k(64)|v(64).
// Q/K MFMA fragments and V segments load DIRECTLY from global (coalesced, every byte
// used once); only the 16x16 P matrix round-trips through LDS (h-row transpose).
__global__ __launch_bounds__(256) void k_attn(const _Float16* __restrict__ qkv,
                                              float* __restrict__ out) {
    __shared__ __align__(16) _Float16 Pb[4][16 * 24];   // P fp16, 48 B row stride
    int tid = threadIdx.x;
    int w = tid >> 6, lane = tid & 63;
    int pos = blockIdx.x * 4 + w;
    _Float16* P = Pb[w];
    const _Float16* src = qkv + (size_t)pos * 3072;
    int l15 = lane & 15, quad = lane >> 4;

    // ---- issue all global loads up-front (V overlaps QK+softmax) ----
    const _Float16* hrow = src + l15 * 192;            // head row l15
    v8h a0 = *(const v8h*)(hrow + quad * 8);           // Q d 0..31
    v8h a1 = *(const v8h*)(hrow + 32 + quad * 8);      // Q d 32..63
    v8h b0 = *(const v8h*)(hrow + 64 + quad * 8);      // K d 0..31
    v8h b1 = *(const v8h*)(hrow + 96 + quad * 8);      // K d 32..63
    int dl = lane & 15;                                // d segment dl*4..+4
    v4h vseg[16];
#pragma unroll
    for (int g = 0; g < 16; g++)
        vseg[g] = *(const v4h*)(src + g * 192 + 128 + dl * 4);

    {   // S = QK^T via 2x mfma_16x16x32; lane holds S[h=quad*4+r][g=l15]
        v4f s = {};
        s = __builtin_amdgcn_mfma_f32_16x16x32_f16(a0, b0, s, 0, 0, 0);
        s = __builtin_amdgcn_mfma_f32_16x16x32_f16(a1, b1, s, 0, 0, 0);
        float e4[4];
#pragma unroll
        for (int r = 0; r < 4; r++) {
            float sv = s[r] - 20.0f;
            e4[r] = (sv > 20.0f || sv < -20.0f) ? 0.0f : __expf(sv);
        }
        // denom: sum over g = sum across l15 (xor 1,2,4,8)
#pragma unroll
        for (int r = 0; r < 4; r++) {
            float t = e4[r];
            t += __shfl_xor(t, 1, 64);
            t += __shfl_xor(t, 2, 64);
            t += __shfl_xor(t, 4, 64);
            t += __shfl_xor(t, 8, 64);
            P[(quad * 4 + r) * 24 + l15] = (_Float16)(e4[r] / t);
        }
    }
    wave_lds_fence();

    {   // out[h][d] = sum_g P[h][g] * V[g][d]
        // lane owns h = 4t + quad for t=0..3, d-range = dl*4 .. +4
        v8h p0[4], p1[4];
#pragma unroll
        for (int t = 0; t < 4; t++) {
            const _Float16* Pr = P + (4 * t + quad) * 24;
            p0[t] = *(const v8h*)Pr;
            p1[t] = *(const v8h*)(Pr + 8);
        }
        v2h o[4][2] = {};
#pragma unroll
        for (int g = 0; g < 16; g++) {
            v2h va; va[0] = vseg[g][0]; va[1] = vseg[g][1];
            v2h vb; vb[0] = vseg[g][2]; vb[1] = vseg[g][3];
#pragma unroll
            for (int t = 0; t < 4; t++) {
                _Float16 ph = (g < 8) ? p0[t][g] : p1[t][g - 8];
                v2h p2; p2[0] = ph; p2[1] = ph;
                o[t][0] = p2 * va + o[t][0];
                o[t][1] = p2 * vb + o[t][1];
            }
        }
        float* dst = out + (size_t)pos * 1024;
#pragma unroll
        for (int t = 0; t < 4; t++) {
            float4 v;
            v.x = (float)o[t][0][0];
            v.y = (float)o[t][0][1];
            v.z = (float)o[t][1][0];
            v.w = (float)o[t][1][1];
            *(float4*)(dst + t * 256 + lane * 4) = v;  // fully contiguous per instr
        }
    }
}

extern "C" void kernel_launch(void* const* d_in, const int* in_sizes, int n_in,
                              void* d_out, int out_size, void* d_ws, size_t ws_size,
                              hipStream_t stream) {
    (void)in_sizes; (void)n_in; (void)out_size; (void)ws_size;
    const float* x  = (const float*)d_in[0];  // [4,4096,1024]
    const float* Wq = (const float*)d_in[1];  // [1024,3072]
    const float* bq = (const float*)d_in[2];  // [3072]
    float* out = (float*)d_out;               // [4,4096,16,64] fp32 (64 MiB)

    // x16 (32 MiB) + wt16 (6 MiB) live INSIDE d_out — dead before k_attn overwrites it.
    char* ob = (char*)d_out;
    _Float16* x16   = (_Float16*)ob;                   // 32 MiB @ d_out+0
    _Float16* wt16  = (_Float16*)(ob + (48u << 20));   // 6 MiB  @ d_out+48MiB
    _Float16* qkv16 = (_Float16*)d_ws;                 // 96 MiB

    k_cvt<<<8960, 256, 0, stream>>>(x, x16, Wq, wt16);
    k_gemm<<<768, 512, 0, stream>>>(x16, wt16, bq, qkv16);
    k_attn<<<4096, 256, 0, stream>>>(qkv16, out);
}

// Round 5
// 257.832 us; speedup vs baseline: 1.0642x; 1.0015x over previous
//
#include <hip/hip_runtime.h>

typedef _Float16 v8h __attribute__((ext_vector_type(8)));
typedef _Float16 v4h __attribute__((ext_vector_type(4)));
typedef _Float16 v2h __attribute__((ext_vector_type(2)));
typedef float v4f __attribute__((ext_vector_type(4)));
typedef float f32x16 __attribute__((ext_vector_type(16)));

// ---------------- async global->LDS, 16B per lane ----------------
__device__ __forceinline__ void gl16(const void* g, void* l) {
    __builtin_amdgcn_global_load_lds(
        (const __attribute__((address_space(1))) unsigned int*)g,
        (__attribute__((address_space(3))) unsigned int*)l, 16, 0, 0);
}

// wave-local LDS fence: all outstanding LDS ops complete (wave is lockstep)
__device__ __forceinline__ void wave_lds_fence() {
    asm volatile("s_waitcnt lgkmcnt(0)" ::: "memory");
}

// LDS byte address (32-bit) of a shared-memory pointer, for inline-asm ds ops
__device__ __forceinline__ unsigned lds_addr(const void* p) {
    return (unsigned)(size_t)(const __attribute__((address_space(3))) char*)p;
}

// ---------------- fused converts: x (fp32->fp16) and W (fp32 -> Wt fp16) ----------------
__global__ __launch_bounds__(256) void k_cvt(const float* __restrict__ x,
                                             _Float16* __restrict__ x16,
                                             const float* __restrict__ W,
                                             _Float16* __restrict__ Wt) {
    if (blockIdx.x < 8192) {
        int i = (blockIdx.x * 256 + threadIdx.x) * 8;
        float4 a = *(const float4*)(x + i);
        float4 b = *(const float4*)(x + i + 4);
        v8h h;
        h[0] = (_Float16)a.x; h[1] = (_Float16)a.y; h[2] = (_Float16)a.z; h[3] = (_Float16)a.w;
        h[4] = (_Float16)b.x; h[5] = (_Float16)b.y; h[6] = (_Float16)b.z; h[7] = (_Float16)b.w;
        *(v8h*)(x16 + i) = h;
    } else {
        __shared__ float T[64][68];
        int bid = blockIdx.x - 8192;
        int k0 = (bid & 15) * 64;
        int n0 = (bid >> 4) * 64;
        int t = threadIdx.x;
        int tr = t >> 4;   // 0..15
        int tc = t & 15;   // 0..15
#pragma unroll
        for (int rr = 0; rr < 4; rr++) {
            int kk = rr * 16 + tr;
            float4 v = *(const float4*)(W + (size_t)(k0 + kk) * 3072 + n0 + tc * 4);
            T[kk][tc * 4 + 0] = v.x; T[kk][tc * 4 + 1] = v.y;
            T[kk][tc * 4 + 2] = v.z; T[kk][tc * 4 + 3] = v.w;
        }
        __syncthreads();
#pragma unroll
        for (int ww = 0; ww < 4; ww++) {
            int nn = ww * 16 + tr;
            v4h h;
#pragma unroll
            for (int i = 0; i < 4; i++) h[i] = (_Float16)T[tc * 4 + i][nn];
            *(v4h*)(Wt + (size_t)(n0 + nn) * 1024 + k0 + tc * 4) = h;
        }
    }
}

// ---------------- GEMM: qkv16[16384][3072] = (A(fp16) @ Bt(fp16)^T + bias) as fp16 ----------------
// 256x256 tile, BK=64, 512 threads = 8 waves (2M x 4N), per-wave 128x64 via 4x2 of 32x32.
// mfma_f32_32x32x16_f16; phase = one K=16 step = 8 MFMA/wave; register prefetch one phase
// ahead into the alternate fragment set; counted lgkmcnt(6) + sched_barrier (rule #18).
// LDS swizzle (R4): f(row) = (row&7) ^ ((row>>3)&3). The extra (row>>3)&3 term kills the
// R3 4-way bank alias between rows r,r+8,r+16,r+24 (slots now XOR 0,1,2,3 -> distinct).
// Applied on BOTH sides (rule #21): global source pointer per j (y=(2w+j)&3 wave-uniform)
// and the ds_read slot. Staging ledger: A(t+1)@ph1, B(t+1)@ph2, A(t+2)@ph5, B(t+2)@ph6;
// exact-drain vmcnt(0) gates at ph3/ph7 ends (outstanding == the 8 loads needed next).

#define MFMA32(a, b, c) __builtin_amdgcn_mfma_f32_32x32x16_f16(a, b, c, 0, 0, 0)
#define DSR(d, a, IMM) asm volatile("ds_read_b128 %0, %1 offset:%2" : "=v"(d) : "v"(a), "n"(IMM))
#define LGKM(N) asm volatile("s_waitcnt lgkmcnt(" #N ")" ::: "memory")
#define VMCNT(N) asm volatile("s_waitcnt vmcnt(" #N ")" ::: "memory")
#define SB0() __builtin_amdgcn_sched_barrier(0)
#define BAR() __builtin_amdgcn_s_barrier()
#define PRIO1() __builtin_amdgcn_s_setprio(1)
#define PRIO0() __builtin_amdgcn_s_setprio(0)

// 6 fragment reads for one K=16 step: 4 A m-subtiles (+4096 each) + 2 B n-subtiles
#define RD6(AF, BF, VAK, VBK, IMM)                                      \
    DSR(AF[0], VAK, (IMM));        DSR(AF[1], VAK, (IMM) + 4096);       \
    DSR(AF[2], VAK, (IMM) + 8192); DSR(AF[3], VAK, (IMM) + 12288);     \
    DSR(BF[0], VBK, (IMM));        DSR(BF[1], VBK, (IMM) + 4096);

// 8 MFMAs of one K=16 step (all 8 accumulators, independent)
#define MF8(AF, BF)                                                     \
    _Pragma("unroll")                                                   \
    for (int mi = 0; mi < 4; mi++) {                                    \
        acc[mi][0] = MFMA32(AF[mi], BF[0], acc[mi][0]);                 \
        acc[mi][1] = MFMA32(AF[mi], BF[1], acc[mi][1]);                 \
    }

#define STAGE_A(t, h, j) gl16(aS##j + (size_t)((h) * 128 + (j) * 8) * 1024 + (t) * 64,      \
                              &As[(t) & 1][((h) * 128 + ldsRow + (j) * 8) * 64])
#define STAGE_B(t, h, j) gl16(bS##j + (size_t)((h) * 128 + (j) * 8) * 1024 + (t) * 64,      \
                              &Bs[(t) & 1][((h) * 128 + ldsRow + (j) * 8) * 64])
#define STAGE_A4(t) STAGE_A(t, 0, 0); STAGE_A(t, 0, 1); STAGE_A(t, 1, 0); STAGE_A(t, 1, 1)
#define STAGE_B4(t) STAGE_B(t, 0, 0); STAGE_B(t, 0, 1); STAGE_B(t, 1, 0); STAGE_B(t, 1, 1)

__global__ __launch_bounds__(512, 2) void k_gemm(const _Float16* __restrict__ A,
                                                 const _Float16* __restrict__ Bt,
                                                 const float* __restrict__ bias,
                                                 _Float16* __restrict__ C) {
    __shared__ __align__(16) _Float16 As[2][256 * 64];   // 64 KiB
    __shared__ __align__(16) _Float16 Bs[2][256 * 64];   // 64 KiB

    // grid 64x12 = 768 wg; 768 % 8 == 0 -> simple bijective XCD swizzle (T1)
    int wg = blockIdx.x;
    wg = (wg & 7) * 96 + (wg >> 3);
    int bm = wg / 12, bn = wg % 12;
    int m0 = bm * 256, n0 = bn * 256;

    int tid = threadIdx.x;
    int w = tid >> 6;            // 0..7
    int lane = tid & 63;
    int wm = (w >> 2) * 128;     // 0 or 128
    int wn = (w & 3) * 64;       // 0,64,128,192

    // staging: per-lane global source with inverse-swizzled k slot (rule #21).
    // LDS[row][s] holds global chunk s ^ (row&7) ^ ((row>>3)&3); within a stage call
    // row = base+rl (base = h*128 + w*16 + j*8, mult of 8), so (row>>3)&3 = (2w+j)&3 = y.
    int sl = lane & 7;
    int rl = lane >> 3;                        // == row&7 within the 8-row chunk
    int y0c = (2 * w) & 3, y1c = (2 * w + 1) & 3;
    const _Float16* aS0 = A  + (size_t)(m0 + w * 16 + rl) * 1024 + ((sl ^ rl ^ y0c) * 8);
    const _Float16* aS1 = A  + (size_t)(m0 + w * 16 + rl) * 1024 + ((sl ^ rl ^ y1c) * 8);
    const _Float16* bS0 = Bt + (size_t)(n0 + w * 16 + rl) * 1024 + ((sl ^ rl ^ y0c) * 8);
    const _Float16* bS1 = Bt + (size_t)(n0 + w * 16 + rl) * 1024 + ((sl ^ rl ^ y1c) * 8);
    int ldsRow = w * 16;

    // fragment read bases. 32x32x16 operand layout: row = lane&31, k = (lane>>5)*8 + i.
    // logical 16B slot for k-step kk = kk*2 + (lane>>5); physical = logical ^ x,
    // x = (row&7) ^ ((row>>3)&3). Subtile bases (wm,wn,mi*32,nj*32) are ==0 mod 32 so
    // x computed from lane&31 is valid for every subtile.
    int row = lane & 31;
    int h = lane >> 5;
    int x = (row & 7) ^ ((row >> 3) & 3);
    unsigned aB = lds_addr(&As[0][0]) + (unsigned)((wm + row) * 128);
    unsigned bB = lds_addr(&Bs[0][0]) + (unsigned)((wn + row) * 128);
    unsigned vAk0 = aB + (unsigned)(((0 + h) ^ x) * 16);
    unsigned vAk1 = aB + (unsigned)(((2 + h) ^ x) * 16);
    unsigned vAk2 = aB + (unsigned)(((4 + h) ^ x) * 16);
    unsigned vAk3 = aB + (unsigned)(((6 + h) ^ x) * 16);
    unsigned vBk0 = bB + (unsigned)(((0 + h) ^ x) * 16);
    unsigned vBk1 = bB + (unsigned)(((2 + h) ^ x) * 16);
    unsigned vBk2 = bB + (unsigned)(((4 + h) ^ x) * 16);
    unsigned vBk3 = bB + (unsigned)(((6 + h) ^ x) * 16);

    f32x16 acc[4][2] = {};
    v8h a0f[4], b0f[2];   // fragment set F0
    v8h a1f[4], b1f[2];   // fragment set F1

    // prologue: stage K-tiles 0 (buf0) and 1 (buf1); 16 gl16
    STAGE_A4(0); STAGE_B4(0);
    STAGE_A4(1); STAGE_B4(1);
    VMCNT(8);                 // tile 0 landed; tile 1 (newest 8) in flight
    BAR();
    RD6(a0f, b0f, vAk0, vBk0, 0)   // F0 <- kk0 buf0

    for (int it = 0; it < 8; ++it) {
        int t = it * 2;
        // ph1: use F0 (kk0 b0); fill F1 <- kk1 b0; stage A(t+1) -> As[1]
        RD6(a1f, b1f, vAk1, vBk1, 0)
        if (it >= 1) { STAGE_A4(t + 1); }
        LGKM(6); SB0(); PRIO1();
        MF8(a0f, b0f)
        PRIO0(); BAR();
        // ph2: use F1 (kk1 b0); fill F0 <- kk2 b0; stage B(t+1) -> Bs[1]
        RD6(a0f, b0f, vAk2, vBk2, 0)
        if (it >= 1) { STAGE_B4(t + 1); }
        LGKM(6); SB0(); PRIO1();
        MF8(a1f, b1f)
        PRIO0(); BAR();
        // ph3: use F0 (kk2 b0); fill F1 <- kk3 b0; GATE: drain A(t+1),B(t+1) (exact 8)
        RD6(a1f, b1f, vAk3, vBk3, 0)
        LGKM(6); SB0(); PRIO1();
        MF8(a0f, b0f)
        PRIO0();
        VMCNT(0);
        BAR();
        // ph4: use F1 (kk3 b0); fill F0 <- kk0 buf1 (gated above)
        RD6(a0f, b0f, vAk0, vBk0, 32768)
        LGKM(6); SB0(); PRIO1();
        MF8(a1f, b1f)
        PRIO0(); BAR();
        // ph5: use F0 (kk0 b1); fill F1 <- kk1 b1; stage A(t+2) -> As[0]
        RD6(a1f, b1f, vAk1, vBk1, 32768)
        if (it <= 6) { STAGE_A4(t + 2); }
        LGKM(6); SB0(); PRIO1();
        MF8(a0f, b0f)
        PRIO0(); BAR();
        // ph6: use F1 (kk1 b1); fill F0 <- kk2 b1; stage B(t+2) -> Bs[0]
        RD6(a0f, b0f, vAk2, vBk2, 32768)
        if (it <= 6) { STAGE_B4(t + 2); }
        LGKM(6); SB0(); PRIO1();
        MF8(a1f, b1f)
        PRIO0(); BAR();
        // ph7: use F0 (kk2 b1); fill F1 <- kk3 b1; GATE: drain A(t+2),B(t+2) (exact 8)
        RD6(a1f, b1f, vAk3, vBk3, 32768)
        LGKM(6); SB0(); PRIO1();
        MF8(a0f, b0f)
        PRIO0();
        VMCNT(0);
        BAR();
        // ph8: use F1 (kk3 b1); fill F0 <- kk0 buf0 of next iteration (gated above)
        if (it <= 6) {
            RD6(a0f, b0f, vAk0, vBk0, 0)
            LGKM(6);
        } else {
            LGKM(0);
        }
        SB0(); PRIO1();
        MF8(a1f, b1f)
        PRIO0(); BAR();
    }

    // epilogue: 32x32 C/D layout: col = lane&31, row = (r&3) + 8*(r>>2) + 4*(lane>>5)
    int cl = lane & 31;
    int rq = (lane >> 5) * 4;
#pragma unroll
    for (int nj = 0; nj < 2; nj++) {
        int n = n0 + wn + nj * 32 + cl;
        float bv = bias[n];
#pragma unroll
        for (int mi = 0; mi < 4; mi++) {
            int mb = m0 + wm + mi * 32 + rq;
#pragma unroll
            for (int r = 0; r < 16; r++) {
                int m = mb + (r & 3) + 8 * (r >> 2);
                C[(size_t)m * 3072 + n] = (_Float16)(acc[mi][nj][r] + bv);
            }
        }
    }
}

// ---------------- attention: one wave per position, global-direct fragments ----------------
// qkv row layout per pos: head h occupies halves [h*192, h*192+192): q(64)|k(64)|v(64).
// Q/K MFMA fragments and V segments load DIRECTLY from global (coalesced, every byte
// used once); only the 16x16 P matrix round-trips through LDS (h-row transpose).
__global__ __launch_bounds__(256) void k_attn(const _Float16* __restrict__ qkv,
                                              float* __restrict__ out) {
    __shared__ __align__(16) _Float16 Pb[4][16 * 24];   // P fp16, 48 B row stride
    int tid = threadIdx.x;
    int w = tid >> 6, lane = tid & 63;
    int pos = blockIdx.x * 4 + w;
    _Float16* P = Pb[w];
    const _Float16* src = qkv + (size_t)pos * 3072;
    int l15 = lane & 15, quad = lane >> 4;

    // ---- issue all global loads up-front (V overlaps QK+softmax) ----
    const _Float16* hrow = src + l15 * 192;            // head row l15
    v8h a0 = *(const v8h*)(hrow + quad * 8);           // Q d 0..31
    v8h a1 = *(const v8h*)(hrow + 32 + quad * 8);      // Q d 32..63
    v8h b0 = *(const v8h*)(hrow + 64 + quad * 8);      // K d 0..31
    v8h b1 = *(const v8h*)(hrow + 96 + quad * 8);      // K d 32..63
    int dl = lane & 15;                                // d segment dl*4..+4
    v4h vseg[16];
#pragma unroll
    for (int g = 0; g < 16; g++)
        vseg[g] = *(const v4h*)(src + g * 192 + 128 + dl * 4);

    {   // S = QK^T via 2x mfma_16x16x32; lane holds S[h=quad*4+r][g=l15]
        v4f s = {};
        s = __builtin_amdgcn_mfma_f32_16x16x32_f16(a0, b0, s, 0, 0, 0);
        s = __builtin_amdgcn_mfma_f32_16x16x32_f16(a1, b1, s, 0, 0, 0);
        float e4[4];
#pragma unroll
        for (int r = 0; r < 4; r++) {
            float sv = s[r] - 20.0f;
            e4[r] = (sv > 20.0f || sv < -20.0f) ? 0.0f : __expf(sv);
        }
        // denom: sum over g = sum across l15 (xor 1,2,4,8)
#pragma unroll
        for (int r = 0; r < 4; r++) {
            float t = e4[r];
            t += __shfl_xor(t, 1, 64);
            t += __shfl_xor(t, 2, 64);
            t += __shfl_xor(t, 4, 64);
            t += __shfl_xor(t, 8, 64);
            P[(quad * 4 + r) * 24 + l15] = (_Float16)(e4[r] / t);
        }
    }
    wave_lds_fence();

    {   // out[h][d] = sum_g P[h][g] * V[g][d]
        // lane owns h = 4t + quad for t=0..3, d-range = dl*4 .. +4
        v8h p0[4], p1[4];
#pragma unroll
        for (int t = 0; t < 4; t++) {
            const _Float16* Pr = P + (4 * t + quad) * 24;
            p0[t] = *(const v8h*)Pr;
            p1[t] = *(const v8h*)(Pr + 8);
        }
        v2h o[4][2] = {};
#pragma unroll
        for (int g = 0; g < 16; g++) {
            v2h va; va[0] = vseg[g][0]; va[1] = vseg[g][1];
            v2h vb; vb[0] = vseg[g][2]; vb[1] = vseg[g][3];
#pragma unroll
            for (int t = 0; t < 4; t++) {
                _Float16 ph = (g < 8) ? p0[t][g] : p1[t][g - 8];
                v2h p2; p2[0] = ph; p2[1] = ph;
                o[t][0] = p2 * va + o[t][0];
                o[t][1] = p2 * vb + o[t][1];
            }
        }
        float* dst = out + (size_t)pos * 1024;
#pragma unroll
        for (int t = 0; t < 4; t++) {
            float4 v;
            v.x = (float)o[t][0][0];
            v.y = (float)o[t][0][1];
            v.z = (float)o[t][1][0];
            v.w = (float)o[t][1][1];
            *(float4*)(dst + t * 256 + lane * 4) = v;  // fully contiguous per instr
        }
    }
}

extern "C" void kernel_launch(void* const* d_in, const int* in_sizes, int n_in,
                              void* d_out, int out_size, void* d_ws, size_t ws_size,
                              hipStream_t stream) {
    (void)in_sizes; (void)n_in; (void)out_size; (void)ws_size;
    const float* x  = (const float*)d_in[0];  // [4,4096,1024]
    const float* Wq = (const float*)d_in[1];  // [1024,3072]
    const float* bq = (const float*)d_in[2];  // [3072]
    float* out = (float*)d_out;               // [4,4096,16,64] fp32 (64 MiB)

    // x16 (32 MiB) + wt16 (6 MiB) live INSIDE d_out — dead before k_attn overwrites it.
    char* ob = (char*)d_out;
    _Float16* x16   = (_Float16*)ob;                   // 32 MiB @ d_out+0
    _Float16* wt16  = (_Float16*)(ob + (48u << 20));   // 6 MiB  @ d_out+48MiB
    _Float16* qkv16 = (_Float16*)d_ws;                 // 96 MiB

    k_cvt<<<8960, 256, 0, stream>>>(x, x16, Wq, wt16);
    k_gemm<<<768, 512, 0, stream>>>(x16, wt16, bq, qkv16);
    k_attn<<<4096, 256, 0, stream>>>(qkv16, out);
}